// Round 24
// baseline (59.661 us; speedup 1.0000x reference)
//
#include <hip/hip_runtime.h>
#include <hip/hip_bf16.h>

// ConvexWidthUpsampler R24: R23 with CORRECTED v_permlane32_swap_b32 selects.
// ISA: the instruction swaps vdst's HIGH half (lanes 32..63) with vsrc's LOW
// half (lanes 0..31). With both inputs = v, the returned pair is:
//   pr.x = low-broadcast  (lane<32 ? v[lane] : v[lane-32])
//   pr.y = high-broadcast (lane<32 ? v[lane+32] : v[lane])
// => partner(lane^32) value = lo ? pr.x : pr.y   (R23 had this inverted).
// Zero-LDS 32x32x16 MFMA, 2 px/thread (one image row per block iter).
// Round 1: z = mfma(B1,a) (K=16). Packed |z| re-enters as B-operand under
// ch(k)=(k&3)+8((k>>2)&1)+4(k>>3) (M2 pre-permuted lo/hi in prep).
// Round 2: m = mfma(B2a,a)+mfma(M2pL,zfL)+mfma(M2pH,zfH); D-reg r ->
// (k,v)=(r/3 [+5 if lo], r%3); invalid rows bias=-100 -> exp2 -> 0.
// B=16,C=1,H=512,W=512,up=(1,3). Output [16,1,512,1536] f32.

#define BB 16
#define HH 512
#define WW 512
#define HID 32
#define NM 27
#define LOG2E 1.44269504088896340736f
#define ND 8192      // double-tiles: one image row (512 px) each
#define NBLK 1024    // 8 rows per block

typedef short bf16x8 __attribute__((ext_vector_type(8)));
typedef float f32x16 __attribute__((ext_vector_type(16)));
typedef unsigned int u32;
typedef u32 u32x2 __attribute__((ext_vector_type(2)));

#define ZERO16 (f32x16){0.f,0.f,0.f,0.f,0.f,0.f,0.f,0.f,0.f,0.f,0.f,0.f,0.f,0.f,0.f,0.f}

__device__ __forceinline__ u32 pk2(float a, float b) {
    union { __hip_bfloat162 h2; u32 u; } cv;
    cv.h2 = __float22bfloat162_rn(make_float2(a, b));
    return cv.u;
}
__device__ __forceinline__ float blo(u32 w) { return __uint_as_float(w << 16); }
__device__ __forceinline__ float bhi(u32 w) { return __uint_as_float(w & 0xffff0000u); }

// xor-32 exchange on the VALU pipe. partner = lo ? .x : .y  (see header).
__device__ __forceinline__ u32x2 swap32(u32 v) {
    return __builtin_amdgcn_permlane32_swap(v, v, false, false);
}

// ws bf16 layout, 4 sections x [32 n][16 c] = 2048 elems (4 KB) -- identical
// to R20/R21/R22 (hardware-proven).
__global__ void prep_B(const float* __restrict__ w1, const float* __restrict__ b1,
                       const float* __restrict__ alpha, const float* __restrict__ w2,
                       const float* __restrict__ b2, __hip_bfloat16* __restrict__ ws) {
    const int i = blockIdx.x * 256 + threadIdx.x;
    if (i >= 2048) return;
    const int sec = i >> 9;
    const int rr  = i & 511;
    const int n   = rr >> 4, c = rr & 15;
    const int lo  = (n >> 2) & 1;
    const int r   = (n & 3) + 4 * (n >> 3);
    const bool valid = lo == 0 ? (r < 15) : (r < 12);
    const int k = (lo == 0) ? (r / 3) : (5 + r / 3);
    const int j = 3 * k + (r % 3);
    const int ch = (c & 3) + 8 * ((c >> 2) & 1) + 4 * (c >> 3);
    float v = 0.0f;
    if (sec == 0) {
        if (valid) {
            if (c < 9) {
                for (int q = 0; q < HID; ++q)
                    v += w2[j * HID + q] * (0.5f * (1.0f + alpha[q])) * w1[q * 9 + c];
                v *= LOG2E;
            } else if (c == 9) {
                v = b2[j];
                for (int q = 0; q < HID; ++q)
                    v += w2[j * HID + q] * (0.5f * (1.0f + alpha[q])) * b1[q];
                v *= LOG2E;
            }
        } else if (c == 9) {
            v = -100.0f;   // mask row: logit=-100 -> exp2 ~ 0
        }
    } else if (sec == 1) {
        if (valid) v = w2[j * HID + ch] * (0.5f * (1.0f - alpha[ch])) * LOG2E;
    } else if (sec == 2) {
        if (valid) v = w2[j * HID + 16 + ch] * (0.5f * (1.0f - alpha[16 + ch])) * LOG2E;
    } else {
        v = (c < 9) ? w1[n * 9 + c] : (c == 9 ? b1[n] : 0.0f);
    }
    ws[i] = __float2bfloat16(v);
}

// Load both chains' 3x3 windows for image row d (shared row clamps).
__device__ __forceinline__ void load_row2(const float* __restrict__ x, int d,
                                          int tid, float a[9], float b[9]) {
    const int hrow = d & (HH - 1);     // scalar
    const int bidx = d >> 9;           // scalar
    const float* xb = x + (size_t)bidx * (HH * WW);
    const float* rp[3]; bool hok[3];
#pragma unroll
    for (int i = 0; i < 3; ++i) {
        const int h = hrow + i - 1;
        hok[i] = (unsigned)h < (unsigned)HH;
        const int hy = h < 0 ? 0 : (h > HH - 1 ? HH - 1 : h);
        rp[i] = xb + hy * WW;
    }
    const int wa = tid;          // chain A col
    const int wb = 256 + tid;    // chain B col
    int wxa[3], wxb[3]; bool woka[3], wokb[3];
#pragma unroll
    for (int i = 0; i < 3; ++i) {
        const int qa = wa + i - 1;
        woka[i] = (unsigned)qa < (unsigned)WW;
        wxa[i]  = qa < 0 ? 0 : (qa > WW - 1 ? WW - 1 : qa);
        const int qb = wb + i - 1;
        wokb[i] = (unsigned)qb < (unsigned)WW;
        wxb[i]  = qb < 0 ? 0 : (qb > WW - 1 ? WW - 1 : qb);
    }
#pragma unroll
    for (int ki = 0; ki < 3; ++ki)
#pragma unroll
        for (int kj = 0; kj < 3; ++kj) {
            const float va = rp[ki][wxa[kj]];
            const float vb = rp[ki][wxb[kj]];
            a[ki * 3 + kj] = (hok[ki] && woka[kj]) ? va : 0.0f;
            b[ki * 3 + kj] = (hok[ki] && wokb[kj]) ? vb : 0.0f;
        }
}

// Full per-pixel pipeline: pack -> permlane exchange -> fragments -> z MFMA
// -> |z| repack -> logits MFMAs -> in-register softmax -> permlane reduce ->
// store own pixel.
__device__ __forceinline__ void process_px(
    const float xv[9], bf16x8 B2a, bf16x8 M2pL, bf16x8 M2pH, bf16x8 B1f,
    int lo, float* __restrict__ out, size_t ob)
{
    u32 pw[5] = {pk2(xv[0], xv[1]), pk2(xv[2], xv[3]), pk2(xv[4], xv[5]),
                 pk2(xv[6], xv[7]), pk2(xv[8], 1.0f)};
    u32x2 pr[5];
#pragma unroll
    for (int i = 0; i < 5; ++i) pr[i] = swap32(pw[i]);
    // partner(lane^32) word i = lo ? pr[i].x : pr[i].y

    union { u32 u[4]; bf16x8 h; } fa, fb;
    fa.u[0] = lo ? pr[4].x : pw[0];
    fa.u[1] = lo ? 0u      : pw[1];
    fa.u[2] = lo ? 0u      : pw[2];
    fa.u[3] = lo ? 0u      : pw[3];
    fb.u[0] = lo ? pw[4]   : pr[0].y;
    fb.u[1] = lo ? 0u      : pr[1].y;
    fb.u[2] = lo ? 0u      : pr[2].y;
    fb.u[3] = lo ? 0u      : pr[3].y;

    float xsel[2][5];
    xsel[0][0] = lo ? bhi(pr[2].x) : xv[0];
    xsel[0][1] = lo ? blo(pr[3].x) : xv[1];
    xsel[0][2] = lo ? bhi(pr[3].x) : xv[2];
    xsel[0][3] = lo ? blo(pr[4].x) : xv[3];
    xsel[0][4] = lo ? 0.0f         : xv[4];
    xsel[1][0] = lo ? xv[5] : blo(pr[0].y);
    xsel[1][1] = lo ? xv[6] : bhi(pr[0].y);
    xsel[1][2] = lo ? xv[7] : blo(pr[1].y);
    xsel[1][3] = lo ? xv[8] : bhi(pr[1].y);
    xsel[1][4] = lo ? 0.0f  : blo(pr[2].y);

    float num[2][3], den[2][3];
#pragma unroll
    for (int f = 0; f < 2; ++f) {
        const bf16x8 a = f ? fb.h : fa.h;
        f32x16 zz = ZERO16;
        zz = __builtin_amdgcn_mfma_f32_32x32x16_bf16(B1f, a, zz, 0, 0, 0);
        union { u32 u[8]; bf16x8 h[2]; } zf;
#pragma unroll
        for (int i = 0; i < 8; ++i)
            zf.u[i] = pk2(fabsf(zz[2 * i]), fabsf(zz[2 * i + 1]));
        f32x16 m = ZERO16;
        m = __builtin_amdgcn_mfma_f32_32x32x16_bf16(B2a,  a,       m, 0, 0, 0);
        m = __builtin_amdgcn_mfma_f32_32x32x16_bf16(M2pL, zf.h[0], m, 0, 0, 0);
        m = __builtin_amdgcn_mfma_f32_32x32x16_bf16(M2pH, zf.h[1], m, 0, 0, 0);
        float nu[3] = {0.f, 0.f, 0.f}, de[3] = {0.f, 0.f, 0.f};
#pragma unroll
        for (int r = 0; r < 15; ++r) {
            const float e = __builtin_amdgcn_exp2f(m[r]);
            de[r % 3] += e;
            nu[r % 3] = fmaf(xsel[f][r / 3], e, nu[r % 3]);
        }
#pragma unroll
        for (int v = 0; v < 3; ++v) { num[f][v] = nu[v]; den[f][v] = de[v]; }
    }

    // pair-reduction: each lane needs only its OWN fragment's sum; partner's
    // "other"-fragment partial IS my fragment. partner = lo ? .x : .y.
#pragma unroll
    for (int v = 0; v < 3; ++v) {
        float own_n = lo ? num[1][v] : num[0][v];
        float oth_n = lo ? num[0][v] : num[1][v];
        float own_d = lo ? den[1][v] : den[0][v];
        float oth_d = lo ? den[0][v] : den[1][v];
        const u32x2 pn = swap32(__float_as_uint(oth_n));
        const u32x2 pd = swap32(__float_as_uint(oth_d));
        own_n += __uint_as_float(lo ? pn.x : pn.y);
        own_d += __uint_as_float(lo ? pd.x : pd.y);
        out[ob + v] = own_n * __builtin_amdgcn_rcpf(own_d);
    }
}

__global__ __launch_bounds__(256, 2) void convex_upsample_pl2(
    const float* __restrict__ x,            // [16,1,512,512]
    const __hip_bfloat16* __restrict__ ws,  // prep output
    float* __restrict__ out)                // [16,1,512,1536]
{
    const int tid  = threadIdx.x;
    const int lane = tid & 63;
    const int lo   = lane >> 5;

    // persistent weight fragments: A-operand row = lane&31, k = lo*8 + i
    const int widx = (lane & 31) * 16 + lo * 8;
    const bf16x8 B2a  = *(const bf16x8*)(ws + widx);
    const bf16x8 M2pL = *(const bf16x8*)(ws + 512 + widx);
    const bf16x8 M2pH = *(const bf16x8*)(ws + 1024 + widx);
    const bf16x8 B1f  = *(const bf16x8*)(ws + 1536 + widx);

    int d = blockIdx.x;
    float xa[9], xb[9];
    load_row2(x, d, tid, xa, xb);

    while (d < ND) {
        const int dn  = d + NBLK;
        const int dpf = (dn < ND) ? dn : 0;
        float na[9], nb[9];
        load_row2(x, dpf, tid, na, nb);   // prefetch next row

        const size_t ob0 = (size_t)(d * 512 + tid) * 3;
        process_px(xa, B2a, M2pL, M2pH, B1f, lo, out, ob0);        // cols 0..255
        process_px(xb, B2a, M2pL, M2pH, B1f, lo, out, ob0 + 768);  // cols 256..511

        d = dn;
#pragma unroll
        for (int k = 0; k < 9; ++k) { xa[k] = na[k]; xb[k] = nb[k]; }
    }
}

extern "C" void kernel_launch(void* const* d_in, const int* in_sizes, int n_in,
                              void* d_out, int out_size, void* d_ws, size_t ws_size,
                              hipStream_t stream) {
    // setup_inputs order: x, target_h, target_w, w1, b1, alpha, w2, b2
    const float* x     = (const float*)d_in[0];
    const float* w1    = (const float*)d_in[3];
    const float* b1    = (const float*)d_in[4];
    const float* alpha = (const float*)d_in[5];
    const float* w2    = (const float*)d_in[6];
    const float* b2    = (const float*)d_in[7];
    float* out = (float*)d_out;
    __hip_bfloat16* ws = (__hip_bfloat16*)d_ws;   // 2048 bf16 = 4 KB

    hipLaunchKernelGGL(prep_B, dim3(8), dim3(256), 0, stream, w1, b1, alpha, w2, b2, ws);
    hipLaunchKernelGGL(convex_upsample_pl2, dim3(NBLK), dim3(256), 0, stream,
                       x, ws, out);
}

// Round 25
// 56.220 us; speedup vs baseline: 1.0612x; 1.0612x over previous
//
#include <hip/hip_runtime.h>
#include <hip/hip_bf16.h>

// ConvexWidthUpsampler R25 (= R22, best measured: 56.3 us): zero-LDS
// 32x32x16 MFMA formulation x 2-pixel-per-thread ILP. A/B vs permlane32_swap
// (R24: 59.7) showed the shfl_xor/ds_bpermute exchange is better -- its
// latency hides under the two independent chains, while permlane adds issue
// pressure to the binding VALU pipe. Keeping the shfl version.
// Each block processes one full image row (512 px) per iteration: chain A =
// cols 0..255, chain B = cols 256..511; chains fully independent.
// Round 1: z = mfma(B1, a) (K=16). Packed |z| re-enters as B-operand under
// ch(k)=(k&3)+8((k>>2)&1)+4(k>>3) (M2 pre-permuted lo/hi in prep).
// Round 2: m = mfma(B2a,a)+mfma(M2pL,zfL)+mfma(M2pH,zfH); D-reg r ->
// (k,v)=(r/3 [+5 if lo], r%3); invalid rows bias=-100 -> exp2 -> 0.
// B=16,C=1,H=512,W=512,up=(1,3). Output [16,1,512,1536] f32.

#define BB 16
#define HH 512
#define WW 512
#define HID 32
#define NM 27
#define LOG2E 1.44269504088896340736f
#define ND 8192      // double-tiles: one image row (512 px) each
#define NBLK 1024    // 8 rows per block

typedef short bf16x8 __attribute__((ext_vector_type(8)));
typedef float f32x16 __attribute__((ext_vector_type(16)));
typedef unsigned int u32;

#define ZERO16 (f32x16){0.f,0.f,0.f,0.f,0.f,0.f,0.f,0.f,0.f,0.f,0.f,0.f,0.f,0.f,0.f,0.f}

__device__ __forceinline__ u32 pk2(float a, float b) {
    union { __hip_bfloat162 h2; u32 u; } cv;
    cv.h2 = __float22bfloat162_rn(make_float2(a, b));
    return cv.u;
}
__device__ __forceinline__ float blo(u32 w) { return __uint_as_float(w << 16); }
__device__ __forceinline__ float bhi(u32 w) { return __uint_as_float(w & 0xffff0000u); }

// ws bf16 layout, 4 sections x [32 n][16 c] = 2048 elems (4 KB) -- identical
// to R20/R21/R22 (hardware-proven).
__global__ void prep_B(const float* __restrict__ w1, const float* __restrict__ b1,
                       const float* __restrict__ alpha, const float* __restrict__ w2,
                       const float* __restrict__ b2, __hip_bfloat16* __restrict__ ws) {
    const int i = blockIdx.x * 256 + threadIdx.x;
    if (i >= 2048) return;
    const int sec = i >> 9;
    const int rr  = i & 511;
    const int n   = rr >> 4, c = rr & 15;
    const int lo  = (n >> 2) & 1;
    const int r   = (n & 3) + 4 * (n >> 3);
    const bool valid = lo == 0 ? (r < 15) : (r < 12);
    const int k = (lo == 0) ? (r / 3) : (5 + r / 3);
    const int j = 3 * k + (r % 3);
    const int ch = (c & 3) + 8 * ((c >> 2) & 1) + 4 * (c >> 3);
    float v = 0.0f;
    if (sec == 0) {
        if (valid) {
            if (c < 9) {
                for (int q = 0; q < HID; ++q)
                    v += w2[j * HID + q] * (0.5f * (1.0f + alpha[q])) * w1[q * 9 + c];
                v *= LOG2E;
            } else if (c == 9) {
                v = b2[j];
                for (int q = 0; q < HID; ++q)
                    v += w2[j * HID + q] * (0.5f * (1.0f + alpha[q])) * b1[q];
                v *= LOG2E;
            }
        } else if (c == 9) {
            v = -100.0f;   // mask row: logit=-100 -> exp2 ~ 0
        }
    } else if (sec == 1) {
        if (valid) v = w2[j * HID + ch] * (0.5f * (1.0f - alpha[ch])) * LOG2E;
    } else if (sec == 2) {
        if (valid) v = w2[j * HID + 16 + ch] * (0.5f * (1.0f - alpha[16 + ch])) * LOG2E;
    } else {
        v = (c < 9) ? w1[n * 9 + c] : (c == 9 ? b1[n] : 0.0f);
    }
    ws[i] = __float2bfloat16(v);
}

// Load both chains' 3x3 windows for image row d (shared row clamps).
__device__ __forceinline__ void load_row2(const float* __restrict__ x, int d,
                                          int tid, float a[9], float b[9]) {
    const int hrow = d & (HH - 1);     // scalar
    const int bidx = d >> 9;           // scalar
    const float* xb = x + (size_t)bidx * (HH * WW);
    const float* rp[3]; bool hok[3];
#pragma unroll
    for (int i = 0; i < 3; ++i) {
        const int h = hrow + i - 1;
        hok[i] = (unsigned)h < (unsigned)HH;
        const int hy = h < 0 ? 0 : (h > HH - 1 ? HH - 1 : h);
        rp[i] = xb + hy * WW;
    }
    const int wa = tid;          // chain A col
    const int wb = 256 + tid;    // chain B col
    int wxa[3], wxb[3]; bool woka[3], wokb[3];
#pragma unroll
    for (int i = 0; i < 3; ++i) {
        const int qa = wa + i - 1;
        woka[i] = (unsigned)qa < (unsigned)WW;
        wxa[i]  = qa < 0 ? 0 : (qa > WW - 1 ? WW - 1 : qa);
        const int qb = wb + i - 1;
        wokb[i] = (unsigned)qb < (unsigned)WW;
        wxb[i]  = qb < 0 ? 0 : (qb > WW - 1 ? WW - 1 : qb);
    }
#pragma unroll
    for (int ki = 0; ki < 3; ++ki)
#pragma unroll
        for (int kj = 0; kj < 3; ++kj) {
            const float va = rp[ki][wxa[kj]];
            const float vb = rp[ki][wxb[kj]];
            a[ki * 3 + kj] = (hok[ki] && woka[kj]) ? va : 0.0f;
            b[ki * 3 + kj] = (hok[ki] && wokb[kj]) ? vb : 0.0f;
        }
}

// Full per-pixel pipeline (R21/R22-proven): pack -> shfl exchange ->
// fragments -> z MFMA -> |z| repack -> logits MFMAs -> in-register softmax
// -> pair-reduce -> store own pixel.
__device__ __forceinline__ void process_px(
    const float xv[9], bf16x8 B2a, bf16x8 M2pL, bf16x8 M2pH, bf16x8 B1f,
    int lo, float* __restrict__ out, size_t ob)
{
    u32 pw[5] = {pk2(xv[0], xv[1]), pk2(xv[2], xv[3]), pk2(xv[4], xv[5]),
                 pk2(xv[6], xv[7]), pk2(xv[8], 1.0f)};
    u32 qw[5];
#pragma unroll
    for (int i = 0; i < 5; ++i)
        qw[i] = (u32)__shfl_xor((int)pw[i], 32, 64);

    union { u32 u[4]; bf16x8 h; } fa, fb;
    fa.u[0] = lo ? qw[4] : pw[0];
    fa.u[1] = lo ? 0u    : pw[1];
    fa.u[2] = lo ? 0u    : pw[2];
    fa.u[3] = lo ? 0u    : pw[3];
    fb.u[0] = lo ? pw[4] : qw[0];
    fb.u[1] = lo ? 0u    : qw[1];
    fb.u[2] = lo ? 0u    : qw[2];
    fb.u[3] = lo ? 0u    : qw[3];

    float xsel[2][5];
    xsel[0][0] = lo ? bhi(qw[2]) : xv[0];
    xsel[0][1] = lo ? blo(qw[3]) : xv[1];
    xsel[0][2] = lo ? bhi(qw[3]) : xv[2];
    xsel[0][3] = lo ? blo(qw[4]) : xv[3];
    xsel[0][4] = lo ? 0.0f       : xv[4];
    xsel[1][0] = lo ? xv[5] : blo(qw[0]);
    xsel[1][1] = lo ? xv[6] : bhi(qw[0]);
    xsel[1][2] = lo ? xv[7] : blo(qw[1]);
    xsel[1][3] = lo ? xv[8] : bhi(qw[1]);
    xsel[1][4] = lo ? 0.0f  : blo(qw[2]);

    float num[2][3], den[2][3];
#pragma unroll
    for (int f = 0; f < 2; ++f) {
        const bf16x8 a = f ? fb.h : fa.h;
        f32x16 zz = ZERO16;
        zz = __builtin_amdgcn_mfma_f32_32x32x16_bf16(B1f, a, zz, 0, 0, 0);
        union { u32 u[8]; bf16x8 h[2]; } zf;
#pragma unroll
        for (int i = 0; i < 8; ++i)
            zf.u[i] = pk2(fabsf(zz[2 * i]), fabsf(zz[2 * i + 1]));
        f32x16 m = ZERO16;
        m = __builtin_amdgcn_mfma_f32_32x32x16_bf16(B2a,  a,       m, 0, 0, 0);
        m = __builtin_amdgcn_mfma_f32_32x32x16_bf16(M2pL, zf.h[0], m, 0, 0, 0);
        m = __builtin_amdgcn_mfma_f32_32x32x16_bf16(M2pH, zf.h[1], m, 0, 0, 0);
        float nu[3] = {0.f, 0.f, 0.f}, de[3] = {0.f, 0.f, 0.f};
#pragma unroll
        for (int r = 0; r < 15; ++r) {
            const float e = __builtin_amdgcn_exp2f(m[r]);
            de[r % 3] += e;
            nu[r % 3] = fmaf(xsel[f][r / 3], e, nu[r % 3]);
        }
#pragma unroll
        for (int v = 0; v < 3; ++v) { num[f][v] = nu[v]; den[f][v] = de[v]; }
    }

#pragma unroll
    for (int f = 0; f < 2; ++f)
#pragma unroll
        for (int v = 0; v < 3; ++v) {
            num[f][v] += __shfl_xor(num[f][v], 32, 64);
            den[f][v] += __shfl_xor(den[f][v], 32, 64);
        }

#pragma unroll
    for (int v = 0; v < 3; ++v) {
        const float nn = lo ? num[1][v] : num[0][v];
        const float dd = lo ? den[1][v] : den[0][v];
        out[ob + v] = nn * __builtin_amdgcn_rcpf(dd);
    }
}

__global__ __launch_bounds__(256, 2) void convex_upsample_x2(
    const float* __restrict__ x,            // [16,1,512,512]
    const __hip_bfloat16* __restrict__ ws,  // prep output
    float* __restrict__ out)                // [16,1,512,1536]
{
    const int tid  = threadIdx.x;
    const int lane = tid & 63;
    const int lo   = lane >> 5;

    // persistent weight fragments: A-operand row = lane&31, k = lo*8 + i
    const int widx = (lane & 31) * 16 + lo * 8;
    const bf16x8 B2a  = *(const bf16x8*)(ws + widx);
    const bf16x8 M2pL = *(const bf16x8*)(ws + 512 + widx);
    const bf16x8 M2pH = *(const bf16x8*)(ws + 1024 + widx);
    const bf16x8 B1f  = *(const bf16x8*)(ws + 1536 + widx);

    int d = blockIdx.x;
    float xa[9], xb[9];
    load_row2(x, d, tid, xa, xb);

    while (d < ND) {
        const int dn  = d + NBLK;
        const int dpf = (dn < ND) ? dn : 0;
        float na[9], nb[9];
        load_row2(x, dpf, tid, na, nb);   // prefetch next row

        const size_t ob0 = (size_t)(d * 512 + tid) * 3;
        process_px(xa, B2a, M2pL, M2pH, B1f, lo, out, ob0);        // cols 0..255
        process_px(xb, B2a, M2pL, M2pH, B1f, lo, out, ob0 + 768);  // cols 256..511

        d = dn;
#pragma unroll
        for (int k = 0; k < 9; ++k) { xa[k] = na[k]; xb[k] = nb[k]; }
    }
}

extern "C" void kernel_launch(void* const* d_in, const int* in_sizes, int n_in,
                              void* d_out, int out_size, void* d_ws, size_t ws_size,
                              hipStream_t stream) {
    // setup_inputs order: x, target_h, target_w, w1, b1, alpha, w2, b2
    const float* x     = (const float*)d_in[0];
    const float* w1    = (const float*)d_in[3];
    const float* b1    = (const float*)d_in[4];
    const float* alpha = (const float*)d_in[5];
    const float* w2    = (const float*)d_in[6];
    const float* b2    = (const float*)d_in[7];
    float* out = (float*)d_out;
    __hip_bfloat16* ws = (__hip_bfloat16*)d_ws;   // 2048 bf16 = 4 KB

    hipLaunchKernelGGL(prep_B, dim3(8), dim3(256), 0, stream, w1, b1, alpha, w2, b2, ws);
    hipLaunchKernelGGL(convex_upsample_x2, dim3(NBLK), dim3(256), 0, stream,
                       x, ws, out);
}